// Round 3
// baseline (4347.603 us; speedup 1.0000x reference)
//
#include <hip/hip_runtime.h>

typedef unsigned short u16;
typedef unsigned int u32;
typedef __attribute__((ext_vector_type(8))) short bf16x8;
typedef __attribute__((ext_vector_type(4))) float f32x4;

#define GLOBAL_AS __attribute__((address_space(1)))
#define LDS_AS __attribute__((address_space(3)))

__device__ __forceinline__ float b2f(u16 u) {
    union { float f; u32 i; } v; v.i = ((u32)u) << 16; return v.f;
}
__device__ __forceinline__ u16 f2b(float f) {
    union { float f; u32 i; } v; v.f = f;
    u32 i = v.i;
    u32 r = (i + 0x7FFFu + ((i >> 16) & 1u)) >> 16;
    return (u16)r;
}
__device__ __forceinline__ float sigm(float x) { return 1.f / (1.f + expf(-x)); }

// ---------------------------------------------------------------------------
// f32 -> bf16 converter (n multiple of 4)
// ---------------------------------------------------------------------------
__global__ void cvt_k(const float* __restrict__ src, u16* __restrict__ dst, int n4)
{
    int id = blockIdx.x * 256 + threadIdx.x;
    if (id >= n4) return;
    float4 v = ((const float4*)src)[id];
    u32 w0 = (u32)f2b(v.x) | ((u32)f2b(v.y) << 16);
    u32 w1 = (u32)f2b(v.z) | ((u32)f2b(v.w) << 16);
    ((u32*)dst)[id * 2]     = w0;
    ((u32*)dst)[id * 2 + 1] = w1;
}

// ---------------------------------------------------------------------------
// Generic GEMM: C[M,N] = A[M,K] @ W[N,K]^T + bias[N]   (m97-pattern, verified)
// ---------------------------------------------------------------------------
template<bool LEAKY, bool REMAP>
__global__ __launch_bounds__(256)
void gemm_bt(const u16* __restrict__ A, const u16* __restrict__ W,
             const float* __restrict__ bias,
             float* __restrict__ Cf, u16* __restrict__ Cb,
             int M, int N, int K)
{
    __shared__ __align__(16) u16 lA[128 * 64];
    __shared__ __align__(16) u16 lB[128 * 64];

    const int tid  = threadIdx.x;
    const int lane = tid & 63;
    const int w    = tid >> 6;
    const int wr   = w >> 1;
    const int wc   = w & 1;
    const int m0   = blockIdx.y * 128;
    const int n0   = blockIdx.x * 128;

    const int lrow = lane & 15;
    const int kgrp = lane >> 4;

    f32x4 acc[4][4] = {};

    for (int k0 = 0; k0 < K; k0 += 64) {
        #pragma unroll
        for (int s = 0; s < 4; ++s) {
            int seg = w * 4 + s;
            int g   = seg * 64 + lane;
            int row = g >> 3;
            int kk  = (g & 7) * 8;
            const u16* gA = A + (size_t)(m0 + row) * K + k0 + kk;
            const u16* gB = W + (size_t)(n0 + row) * K + k0 + kk;
            __builtin_amdgcn_global_load_lds((GLOBAL_AS const void*)gA,
                                             (LDS_AS void*)(&lA[seg * 512]), 16, 0, 0);
            __builtin_amdgcn_global_load_lds((GLOBAL_AS const void*)gB,
                                             (LDS_AS void*)(&lB[seg * 512]), 16, 0, 0);
        }
        __syncthreads();
        #pragma unroll
        for (int kk = 0; kk < 64; kk += 32) {
            bf16x8 af[4], bfr[4];
            #pragma unroll
            for (int i = 0; i < 4; ++i) {
                int ar = wr * 64 + i * 16 + lrow;
                af[i]  = *(const bf16x8*)&lA[ar * 64 + kk + kgrp * 8];
                int br = wc * 64 + i * 16 + lrow;
                bfr[i] = *(const bf16x8*)&lB[br * 64 + kk + kgrp * 8];
            }
            #pragma unroll
            for (int mi = 0; mi < 4; ++mi)
                #pragma unroll
                for (int ni = 0; ni < 4; ++ni)
                    acc[mi][ni] = __builtin_amdgcn_mfma_f32_16x16x32_bf16(
                        af[mi], bfr[ni], acc[mi][ni], 0, 0, 0);
        }
        __syncthreads();
    }

    #pragma unroll
    for (int mi = 0; mi < 4; ++mi) {
        #pragma unroll
        for (int ni = 0; ni < 4; ++ni) {
            int gcol = n0 + wc * 64 + ni * 16 + lrow;
            float bv = bias ? bias[gcol] : 0.f;
            #pragma unroll
            for (int r = 0; r < 4; ++r) {
                int grow = m0 + wr * 64 + mi * 16 + kgrp * 4 + r;
                float v = acc[mi][ni][r] + bv;
                if (LEAKY) v = (v >= 0.f) ? v : 0.02f * v;
                size_t oidx;
                if (REMAP) {
                    int bb = grow & 511, tt = grow >> 9;
                    oidx = ((size_t)bb * 28 + tt) * (size_t)N + gcol;
                } else {
                    oidx = (size_t)grow * (size_t)N + gcol;
                }
                if (Cf) Cf[oidx] = v;
                if (Cb) Cb[oidx] = f2b(v);
            }
        }
    }
}

// ---------------------------------------------------------------------------
// Device-scope grid barrier (cooperative launch guarantees co-residency).
// bar[0] = arrival counter, bar[1] = generation. Zeroed host-side per launch.
// ---------------------------------------------------------------------------
__device__ __forceinline__ void grid_barrier(u32* bar, u32 nwg)
{
    __syncthreads();
    if (threadIdx.x == 0) {
        __threadfence();   // release our global writes
        u32 gen = __hip_atomic_load(&bar[1], __ATOMIC_RELAXED, __HIP_MEMORY_SCOPE_AGENT);
        u32 old = __hip_atomic_fetch_add(&bar[0], 1u, __ATOMIC_ACQ_REL, __HIP_MEMORY_SCOPE_AGENT);
        if (old == nwg - 1u) {
            __hip_atomic_store(&bar[0], 0u, __ATOMIC_RELAXED, __HIP_MEMORY_SCOPE_AGENT);
            __hip_atomic_fetch_add(&bar[1], 1u, __ATOMIC_RELEASE, __HIP_MEMORY_SCOPE_AGENT);
        } else {
            while (__hip_atomic_load(&bar[1], __ATOMIC_ACQUIRE, __HIP_MEMORY_SCOPE_AGENT) == gen)
                __builtin_amdgcn_s_sleep(2);
        }
    }
    __syncthreads();
    __threadfence();       // acquire: invalidate L1 before reading others' writes
}

// ---------------------------------------------------------------------------
// Persistent GRU scan (28 steps, one kernel). Grid 256 = 16 bc x 16 jc.
// wg (bc,jc): owns h rows bc*32..+32, cols jc*32..+32 (h kept in registers).
// LDS: lB = 96 permuted Whh rows {r,z,n}x32 x K512 (resident, swizzled, 96KB)
//      lA = 32 h rows x 512 (re-staged per step via global_load_lds, 32KB)
// One grid barrier per step; h ping-pongs between hb0/hb1 (bf16 global).
// ---------------------------------------------------------------------------
template<bool IS_DEC>
__global__ __launch_bounds__(256, 1)
void scan_coop(const u16* __restrict__ gi,    // enc: [28][512][1536]; dec: [512][1536]
               const u16* __restrict__ Whh,   // [1536][512] bf16
               const float* __restrict__ bhh, // [1536] f32
               const float* __restrict__ h0f, // dec: [512][512] f32 initial h
               u16* __restrict__ hb0,         // ping (enc: zeroed; dec: out0 bf16)
               u16* __restrict__ hb1,         // pong
               const int* __restrict__ xlens, // enc only
               u16* __restrict__ ctx,         // enc: [512][1024] (first half)
               u16* __restrict__ outs,        // dec: [28][512][512] bf16
               u32* __restrict__ bar)
{
    __shared__ __align__(16) u16 lB[96 * 512];   // 96 KB
    __shared__ __align__(16) u16 lA[32 * 512];   // 32 KB

    const int tid  = threadIdx.x;
    const int lane = tid & 63;
    const int w    = tid >> 6;
    const int rh   = w >> 1;            // row half (16 rows)
    const int jh   = w & 1;             // j half (16 cols)
    const int bc   = blockIdx.x >> 4;   // batch chunk (32 rows)
    const int jc   = blockIdx.x & 15;   // j chunk (32 cols)

    const int l15 = lane & 15;
    const int kg  = lane >> 4;          // 0..3

    // ---- stage B once: permuted Whh rows, column-chunk XOR swizzle ----
    #pragma unroll
    for (int s = 0; s < 24; ++s) {
        int g    = s * 256 + tid;
        int rr   = g >> 6;              // LDS row 0..95
        int cp   = g & 63;              // 16B chunk in row
        int gate = rr >> 5;
        int c    = rr & 31;
        int whrow = gate * 512 + jc * 32 + c;
        const u16* src = Whh + (size_t)whrow * 512 + (size_t)((cp ^ (rr & 7)) * 8);
        __builtin_amdgcn_global_load_lds((GLOBAL_AS const void*)src,
            (LDS_AS void*)((char*)lB + (s * 256 + w * 64) * 16), 16, 0, 0);
    }

    // per-lane constants
    const int jloc = jh * 16 + l15;         // 0..31 (col within wg chunk)
    const int j    = jc * 32 + jloc;        // global hidden index
    const int rowb = bc * 32 + rh * 16 + kg * 4;
    const float bhr = bhh[j], bhz = bhh[512 + j], bhn = bhh[1024 + j];

    float h[4];
    float gir[4], giz[4], gin[4];
    int   xl[4];
    #pragma unroll
    for (int r = 0; r < 4; ++r) {
        int row = rowb + r;
        if (IS_DEC) {
            h[r]   = h0f[row * 512 + j];
            gir[r] = b2f(gi[row * 1536 + j]);
            giz[r] = b2f(gi[row * 1536 + 512 + j]);
            gin[r] = b2f(gi[row * 1536 + 1024 + j]);
        } else {
            h[r]  = 0.f;
            xl[r] = xlens[row];
        }
    }
    __syncthreads();   // B resident (syncthreads drains vmcnt)

    const u16* hprev = hb0;
    u16*       hnext = hb1;

    for (int t = 0; t < 28; ++t) {
        // ---- stage A: h rows bc*32..+32 x 512, swizzled source ----
        #pragma unroll
        for (int s = 0; s < 8; ++s) {
            int g   = s * 256 + tid;
            int row = g >> 6;
            int cp  = g & 63;
            const u16* src = hprev + (size_t)(bc * 32 + row) * 512
                                   + (size_t)((cp ^ (row & 7)) * 8);
            __builtin_amdgcn_global_load_lds((GLOBAL_AS const void*)src,
                (LDS_AS void*)((char*)lA + (s * 256 + w * 64) * 16), 16, 0, 0);
        }
        __syncthreads();

        // ---- MFMA: 16 rows x (3 gates x 16 cols), K=512 ----
        f32x4 acc[3] = {};
        const int arow = rh * 16 + l15;
        #pragma unroll 4
        for (int kc = 0; kc < 16; ++kc) {
            int k2 = kc * 64 + kg * 16;   // byte offset of k in row
            bf16x8 a = *(const bf16x8*)((const char*)lA + arow * 1024
                                        + (k2 ^ ((arow & 7) << 4)));
            #pragma unroll
            for (int g3 = 0; g3 < 3; ++g3) {
                int rr = g3 * 32 + jloc;
                bf16x8 b = *(const bf16x8*)((const char*)lB + rr * 1024
                                            + (k2 ^ ((rr & 7) << 4)));
                acc[g3] = __builtin_amdgcn_mfma_f32_16x16x32_bf16(a, b, acc[g3], 0, 0, 0);
            }
        }

        // ---- gate (r,z,n same lane/reg) ----
        const u16* gi_t = IS_DEC ? gi : gi + (size_t)t * 512 * 1536;
        #pragma unroll
        for (int r = 0; r < 4; ++r) {
            int row = rowb + r;
            float ir, iz, in_;
            if (IS_DEC) { ir = gir[r]; iz = giz[r]; in_ = gin[r]; }
            else {
                ir  = b2f(gi_t[row * 1536 + j]);
                iz  = b2f(gi_t[row * 1536 + 512 + j]);
                in_ = b2f(gi_t[row * 1536 + 1024 + j]);
            }
            float rg = sigm(ir + acc[0][r] + bhr);
            float zg = sigm(iz + acc[1][r] + bhz);
            float ng = tanhf(in_ + rg * (acc[2][r] + bhn));
            float hn = (1.f - zg) * ng + zg * h[r];
            h[r] = hn;
            hnext[row * 512 + j] = f2b(hn);
            if (IS_DEC) outs[((size_t)t * 512 + row) * 512 + j] = f2b(hn);
            else if (xl[r] - 1 == t) ctx[row * 1024 + j] = f2b(hn);
        }

        grid_barrier(bar, gridDim.x);
        const u16* tmp = hprev; hprev = hnext; hnext = (u16*)tmp;
    }
}

// ---------------------------------------------------------------------------
// Embedding gather f32 -> bf16 (+ last valid token)
// ---------------------------------------------------------------------------
__global__ void embed_k(const int* __restrict__ x, const int* __restrict__ xlens,
                        const float* __restrict__ emb,
                        u16* __restrict__ embedded, u16* __restrict__ x_last)
{
    int id = blockIdx.x * 256 + threadIdx.x;   // 28*512*128
    if (id >= 28 * 512 * 128) return;
    int e2 = id & 127;
    int tb = id >> 7;
    int b  = tb & 511;
    int t  = tb >> 9;
    int tok = x[b * 28 + t];
    const float* src = emb + (size_t)tok * 256 + e2 * 2;
    u32 v = (u32)f2b(src[0]) | ((u32)f2b(src[1]) << 16);
    *(u32*)(embedded + (size_t)tb * 256 + e2 * 2) = v;
    if (t == xlens[b] - 1)
        *(u32*)(x_last + (size_t)b * 256 + e2 * 2) = v;
}

// ---------------------------------------------------------------------------
// Backward-direction context: single GRU step with h0 = 0.
// ---------------------------------------------------------------------------
__global__ void ctxb_k(const float* __restrict__ gi, const float* __restrict__ bhh,
                       u16* __restrict__ ctx)
{
    int idx = blockIdx.x * 256 + threadIdx.x;
    if (idx >= 512 * 512) return;
    int b = idx >> 9, j = idx & 511;
    int base = b * 1536;
    float r = sigm(gi[base + j] + bhh[j]);
    float z = sigm(gi[base + 512 + j] + bhh[512 + j]);
    float n = tanhf(gi[base + 1024 + j] + r * bhh[1024 + j]);
    ctx[b * 1024 + 512 + j] = f2b((1.f - z) * n);
}

// ---------------------------------------------------------------------------

extern "C" void kernel_launch(void* const* d_in, const int* in_sizes, int n_in,
                              void* d_out, int out_size, void* d_ws, size_t ws_size,
                              hipStream_t stream)
{
    const int*   x      = (const int*)d_in[0];
    const int*   xlens  = (const int*)d_in[1];
    const float* emb    = (const float*)d_in[2];
    const float* Wih_f  = (const float*)d_in[3];
    const float* Whh_f  = (const float*)d_in[4];
    const float* bih_f  = (const float*)d_in[5];
    const float* bhh_f  = (const float*)d_in[6];
    const float* Wih_b  = (const float*)d_in[7];
    const float* bih_b  = (const float*)d_in[9];
    const float* bhh_b  = (const float*)d_in[10];
    const float* fc1_w  = (const float*)d_in[11];
    const float* fc1_b  = (const float*)d_in[12];
    const float* fc2_w  = (const float*)d_in[13];
    const float* fc2_b  = (const float*)d_in[14];
    const float* dWih   = (const float*)d_in[15];
    const float* dWhh   = (const float*)d_in[16];
    const float* dbih   = (const float*)d_in[17];
    const float* dbhh   = (const float*)d_in[18];
    const float* re_w   = (const float*)d_in[19];
    const float* re_b   = (const float*)d_in[20];
    const float* hv_w   = (const float*)d_in[21];
    const float* hv_b   = (const float*)d_in[22];

    float* out        = (float*)d_out;
    float* out_logits = out;                                   // [28,512,32000] f32
    float* out_z      = out + (size_t)28 * 512 * 32000;        // [512,128] f32
    float* out_re     = out_z + 512 * 128;                     // [512,28,256] f32

    // --- ws sub-allocator ---
    char* ws = (char*)d_ws;
    size_t off = 0;
    auto alloc = [&](size_t bytes) -> void* {
        void* p = ws + off; off += (bytes + 255) & ~(size_t)255; return p;
    };
    u16* wWihf = (u16*)alloc(1536 * 256 * 2);
    u16* wWhhf = (u16*)alloc(1536 * 512 * 2);
    u16* wWihb = (u16*)alloc(1536 * 256 * 2);
    u16* wfc1  = (u16*)alloc(128 * 1024 * 2);
    u16* wfc2  = (u16*)alloc(512 * 128 * 2);
    u16* wdWih = (u16*)alloc(1536 * 512 * 2);
    u16* wdWhh = (u16*)alloc(1536 * 512 * 2);
    u16* wre   = (u16*)alloc(256 * 512 * 2);
    u16* whv   = (u16*)alloc((size_t)32000 * 512 * 2);
    u16*   hb0    = (u16*)  alloc(512 * 512 * 2);
    u16*   hb1    = (u16*)  alloc(512 * 512 * 2);
    u16*   ctx    = (u16*)  alloc(512 * 1024 * 2);
    float* gi_bw  = (float*)alloc(512 * 1536 * 4);
    float* out0f  = (float*)alloc(512 * 512 * 4);
    u16*   out_zb = (u16*)  alloc(512 * 128 * 2);
    u16*   gi_dec = (u16*)  alloc(512 * 1536 * 2);
    u16*   outsb  = (u16*)  alloc((size_t)28 * 512 * 512 * 2);
    u32*   bars   = (u32*)  alloc(64);

    // --- big transient scratch overlaid into logits region of d_out ---
    char* ds = (char*)d_out;
    size_t doff = 0;
    auto dalloc = [&](size_t bytes) -> void* {
        void* p = ds + doff; doff += (bytes + 255) & ~(size_t)255; return p;
    };
    u16* embedded = (u16*)dalloc((size_t)28 * 512 * 256 * 2);
    u16* x_last   = (u16*)dalloc(512 * 256 * 2);
    u16* gi_f     = (u16*)dalloc((size_t)28 * 512 * 1536 * 2);

    // 0. weight conversion + state init
    auto cvt = [&](const float* s, u16* d, int n) {
        cvt_k<<<(n / 4 + 255) / 256, 256, 0, stream>>>(s, d, n / 4);
    };
    cvt(Wih_f, wWihf, 1536 * 256);
    cvt(Whh_f, wWhhf, 1536 * 512);
    cvt(Wih_b, wWihb, 1536 * 256);
    cvt(fc1_w, wfc1, 128 * 1024);
    cvt(fc2_w, wfc2, 512 * 128);
    cvt(dWih, wdWih, 1536 * 512);
    cvt(dWhh, wdWhh, 1536 * 512);
    cvt(re_w, wre, 256 * 512);
    cvt(hv_w, whv, 32000 * 512);
    hipMemsetAsync(bars, 0, 64, stream);
    hipMemsetAsync(hb0, 0, 512 * 512 * 2, stream);

    // 1. embedding gather
    embed_k<<<7168, 256, 0, stream>>>(x, xlens, emb, embedded, x_last);

    // 2. encoder input gates for all t: gi_f = embedded @ Wih_f^T + bih_f
    gemm_bt<false, false><<<dim3(12, 112), 256, 0, stream>>>(
        embedded, wWihf, bih_f, nullptr, gi_f, 14336, 1536, 256);

    // 3. forward encoder scan — one cooperative kernel
    {
        const u16* a0 = gi_f;  const u16* a1 = wWhhf;  const float* a2 = bhh_f;
        const float* a3 = nullptr;  u16* a4 = hb0;  u16* a5 = hb1;
        const int* a6 = xlens;  u16* a7 = ctx;  u16* a8 = nullptr;  u32* a9 = bars;
        void* args[] = { &a0,&a1,&a2,&a3,&a4,&a5,&a6,&a7,&a8,&a9 };
        hipLaunchCooperativeKernel((void*)scan_coop<false>, dim3(256), dim3(256),
                                   args, 0, stream);
    }

    // 4. backward-direction context
    gemm_bt<false, false><<<dim3(12, 4), 256, 0, stream>>>(
        x_last, wWihb, bih_b, gi_bw, nullptr, 512, 1536, 256);
    ctxb_k<<<1024, 256, 0, stream>>>(gi_bw, bhh_b, ctx);

    // 5. z = context @ fc1_w^T + fc1_b
    gemm_bt<false, false><<<dim3(1, 4), 256, 0, stream>>>(
        ctx, wfc1, fc1_b, out_z, out_zb, 512, 128, 1024);

    // 6. out0 = z @ fc2_w^T + fc2_b  (bf16 copy straight into hb0 = decoder h ping)
    gemm_bt<false, false><<<dim3(4, 4), 256, 0, stream>>>(
        out_zb, wfc2, fc2_b, out0f, hb0, 512, 512, 128);

    // 7. decoder constant input gates: gi_dec = out0 @ dec_Wih^T + dec_bih
    gemm_bt<false, false><<<dim3(12, 4), 256, 0, stream>>>(
        hb0, wdWih, dbih, nullptr, gi_dec, 512, 1536, 512);

    // 8. decoder scan — one cooperative kernel
    {
        const u16* a0 = gi_dec;  const u16* a1 = wdWhh;  const float* a2 = dbhh;
        const float* a3 = out0f;  u16* a4 = hb0;  u16* a5 = hb1;
        const int* a6 = nullptr;  u16* a7 = nullptr;  u16* a8 = outsb;
        u32* a9 = bars + 8;
        void* args[] = { &a0,&a1,&a2,&a3,&a4,&a5,&a6,&a7,&a8,&a9 };
        hipLaunchCooperativeKernel((void*)scan_coop<true>, dim3(256), dim3(256),
                                   args, 0, stream);
    }

    // 9. re_emb = leakyrelu(outs @ re_w^T + re_b), [T,B]->[B,T]
    gemm_bt<true, true><<<dim3(2, 112), 256, 0, stream>>>(
        outsb, wre, re_b, out_re, nullptr, 14336, 256, 512);

    // 10. logits = outs @ hv_w^T + hv_b  (overwrites d_out scratch)
    gemm_bt<false, false><<<dim3(250, 112), 256, 0, stream>>>(
        outsb, whv, hv_b, out_logits, nullptr, 14336, 32000, 512);
}

// Round 4
// 1480.774 us; speedup vs baseline: 2.9360x; 2.9360x over previous
//
#include <hip/hip_runtime.h>

typedef unsigned short u16;
typedef unsigned int u32;
typedef __attribute__((ext_vector_type(8))) short bf16x8;
typedef __attribute__((ext_vector_type(4))) float f32x4;

#define GLOBAL_AS __attribute__((address_space(1)))
#define LDS_AS __attribute__((address_space(3)))

__device__ __forceinline__ float b2f(u16 u) {
    union { float f; u32 i; } v; v.i = ((u32)u) << 16; return v.f;
}
__device__ __forceinline__ u16 f2b(float f) {
    union { float f; u32 i; } v; v.f = f;
    u32 i = v.i;
    u32 r = (i + 0x7FFFu + ((i >> 16) & 1u)) >> 16;
    return (u16)r;
}
__device__ __forceinline__ float sigm(float x) { return 1.f / (1.f + expf(-x)); }

// ---------------------------------------------------------------------------
// f32 -> bf16 converter (n multiple of 4)
// ---------------------------------------------------------------------------
__global__ void cvt_k(const float* __restrict__ src, u16* __restrict__ dst, int n4)
{
    int id = blockIdx.x * 256 + threadIdx.x;
    if (id >= n4) return;
    float4 v = ((const float4*)src)[id];
    u32 w0 = (u32)f2b(v.x) | ((u32)f2b(v.y) << 16);
    u32 w1 = (u32)f2b(v.z) | ((u32)f2b(v.w) << 16);
    ((u32*)dst)[id * 2]     = w0;
    ((u32*)dst)[id * 2 + 1] = w1;
}

// ---------------------------------------------------------------------------
// Generic GEMM: C[M,N] = A[M,K] @ W[N,K]^T + bias[N]   (m97-pattern, verified)
// ---------------------------------------------------------------------------
template<bool LEAKY, bool REMAP>
__global__ __launch_bounds__(256)
void gemm_bt(const u16* __restrict__ A, const u16* __restrict__ W,
             const float* __restrict__ bias,
             float* __restrict__ Cf, u16* __restrict__ Cb,
             int M, int N, int K)
{
    __shared__ __align__(16) u16 lA[128 * 64];
    __shared__ __align__(16) u16 lB[128 * 64];

    const int tid  = threadIdx.x;
    const int lane = tid & 63;
    const int w    = tid >> 6;
    const int wr   = w >> 1;
    const int wc   = w & 1;
    const int m0   = blockIdx.y * 128;
    const int n0   = blockIdx.x * 128;

    const int lrow = lane & 15;
    const int kgrp = lane >> 4;

    f32x4 acc[4][4] = {};

    for (int k0 = 0; k0 < K; k0 += 64) {
        #pragma unroll
        for (int s = 0; s < 4; ++s) {
            int seg = w * 4 + s;
            int g   = seg * 64 + lane;
            int row = g >> 3;
            int kk  = (g & 7) * 8;
            const u16* gA = A + (size_t)(m0 + row) * K + k0 + kk;
            const u16* gB = W + (size_t)(n0 + row) * K + k0 + kk;
            __builtin_amdgcn_global_load_lds((GLOBAL_AS const void*)gA,
                                             (LDS_AS void*)(&lA[seg * 512]), 16, 0, 0);
            __builtin_amdgcn_global_load_lds((GLOBAL_AS const void*)gB,
                                             (LDS_AS void*)(&lB[seg * 512]), 16, 0, 0);
        }
        __syncthreads();
        #pragma unroll
        for (int kk = 0; kk < 64; kk += 32) {
            bf16x8 af[4], bfr[4];
            #pragma unroll
            for (int i = 0; i < 4; ++i) {
                int ar = wr * 64 + i * 16 + lrow;
                af[i]  = *(const bf16x8*)&lA[ar * 64 + kk + kgrp * 8];
                int br = wc * 64 + i * 16 + lrow;
                bfr[i] = *(const bf16x8*)&lB[br * 64 + kk + kgrp * 8];
            }
            #pragma unroll
            for (int mi = 0; mi < 4; ++mi)
                #pragma unroll
                for (int ni = 0; ni < 4; ++ni)
                    acc[mi][ni] = __builtin_amdgcn_mfma_f32_16x16x32_bf16(
                        af[mi], bfr[ni], acc[mi][ni], 0, 0, 0);
        }
        __syncthreads();
    }

    #pragma unroll
    for (int mi = 0; mi < 4; ++mi) {
        #pragma unroll
        for (int ni = 0; ni < 4; ++ni) {
            int gcol = n0 + wc * 64 + ni * 16 + lrow;
            float bv = bias ? bias[gcol] : 0.f;
            #pragma unroll
            for (int r = 0; r < 4; ++r) {
                int grow = m0 + wr * 64 + mi * 16 + kgrp * 4 + r;
                float v = acc[mi][ni][r] + bv;
                if (LEAKY) v = (v >= 0.f) ? v : 0.02f * v;
                size_t oidx;
                if (REMAP) {
                    int bb = grow & 511, tt = grow >> 9;
                    oidx = ((size_t)bb * 28 + tt) * (size_t)N + gcol;
                } else {
                    oidx = (size_t)grow * (size_t)N + gcol;
                }
                if (Cf) Cf[oidx] = v;
                if (Cb) Cb[oidx] = f2b(v);
            }
        }
    }
}

// ---------------------------------------------------------------------------
// Fused GRU scan step — ONE kernel per time step (kernel boundary = sync).
// Grid 256 = 16 bc x 16 jc; wg owns h rows bc*32..+32, cols jc*32..+32.
// LDS: lB = 96 permuted Whh rows {r,z,n}x32cols x K512, XOR-swizzled (96 KB)
//      lA = 32 h rows x 512, XOR-swizzled (32 KB)   [math verified in R2/R3]
// ---------------------------------------------------------------------------
template<bool IS_DEC>
__global__ __launch_bounds__(256)
void scan_step(const u16* __restrict__ gi,      // enc: [28][512][1536]; dec: [512][1536]
               const u16* __restrict__ Whh,     // [1536][512] bf16
               const float* __restrict__ bhh,   // [1536] f32
               const u16* __restrict__ hprev_b, // [512][512] bf16
               const float* __restrict__ hprev_f,// [512][512] f32
               u16* __restrict__ hnext_b,
               float* __restrict__ hnext_f,
               const int* __restrict__ xlens,   // enc only
               u16* __restrict__ ctx,           // enc: [512][1024] (first half)
               u16* __restrict__ outs,          // dec: [28][512][512] bf16
               int t)
{
    __shared__ __align__(16) u16 lB[96 * 512];   // 96 KB
    __shared__ __align__(16) u16 lA[32 * 512];   // 32 KB

    const int tid  = threadIdx.x;
    const int lane = tid & 63;
    const int w    = tid >> 6;
    const int rh   = w >> 1;            // row half (16 rows)
    const int jh   = w & 1;             // j half (16 cols)
    const int bc   = blockIdx.x >> 4;   // batch chunk (32 rows)
    const int jc   = blockIdx.x & 15;   // j chunk (32 cols)

    const int l15 = lane & 15;
    const int kg  = lane >> 4;          // 0..3

    // ---- stage B: permuted Whh rows, column-chunk XOR swizzle ----
    #pragma unroll
    for (int s = 0; s < 24; ++s) {
        int g    = s * 256 + tid;
        int rr   = g >> 6;              // LDS row 0..95
        int cp   = g & 63;              // 16B chunk in row
        int gate = rr >> 5;
        int c    = rr & 31;
        int whrow = gate * 512 + jc * 32 + c;
        const u16* src = Whh + (size_t)whrow * 512 + (size_t)((cp ^ (rr & 7)) * 8);
        __builtin_amdgcn_global_load_lds((GLOBAL_AS const void*)src,
            (LDS_AS void*)((char*)lB + (s * 256 + w * 64) * 16), 16, 0, 0);
    }
    // ---- stage A: h rows bc*32..+32 x 512, swizzled source ----
    #pragma unroll
    for (int s = 0; s < 8; ++s) {
        int g   = s * 256 + tid;
        int row = g >> 6;
        int cp  = g & 63;
        const u16* src = hprev_b + (size_t)(bc * 32 + row) * 512
                                 + (size_t)((cp ^ (row & 7)) * 8);
        __builtin_amdgcn_global_load_lds((GLOBAL_AS const void*)src,
            (LDS_AS void*)((char*)lA + (s * 256 + w * 64) * 16), 16, 0, 0);
    }

    // per-lane constants
    const int jloc = jh * 16 + l15;         // col within wg chunk
    const int j    = jc * 32 + jloc;        // global hidden index
    const int rowb = bc * 32 + rh * 16 + kg * 4;
    const float bhr = bhh[j], bhz = bhh[512 + j], bhn = bhh[1024 + j];

    const u16* gi_t = IS_DEC ? gi : gi + (size_t)t * 512 * 1536;
    float gir[4], giz[4], gin[4], hold[4];
    int   xl[4];
    #pragma unroll
    for (int r = 0; r < 4; ++r) {
        int row = rowb + r;
        gir[r]  = b2f(gi_t[row * 1536 + j]);
        giz[r]  = b2f(gi_t[row * 1536 + 512 + j]);
        gin[r]  = b2f(gi_t[row * 1536 + 1024 + j]);
        hold[r] = hprev_f[row * 512 + j];
        if (!IS_DEC) xl[r] = xlens[row];
    }
    __syncthreads();   // staging complete

    // ---- MFMA: 16 rows x (3 gates x 16 cols), K=512 ----
    f32x4 acc[3] = {};
    const int arow = rh * 16 + l15;
    #pragma unroll 4
    for (int kc = 0; kc < 16; ++kc) {
        int k2 = kc * 64 + kg * 16;   // byte offset of k in row
        bf16x8 a = *(const bf16x8*)((const char*)lA + arow * 1024
                                    + (k2 ^ ((arow & 7) << 4)));
        #pragma unroll
        for (int g3 = 0; g3 < 3; ++g3) {
            int rr = g3 * 32 + jloc;
            bf16x8 b = *(const bf16x8*)((const char*)lB + rr * 1024
                                        + (k2 ^ ((rr & 7) << 4)));
            acc[g3] = __builtin_amdgcn_mfma_f32_16x16x32_bf16(a, b, acc[g3], 0, 0, 0);
        }
    }

    // ---- gate (r,z,n land in same lane/reg) ----
    #pragma unroll
    for (int r = 0; r < 4; ++r) {
        int row = rowb + r;
        float rg = sigm(gir[r] + acc[0][r] + bhr);
        float zg = sigm(giz[r] + acc[1][r] + bhz);
        float ng = tanhf(gin[r] + rg * (acc[2][r] + bhn));
        float hn = (1.f - zg) * ng + zg * hold[r];
        hnext_f[row * 512 + j] = hn;
        hnext_b[row * 512 + j] = f2b(hn);
        if (IS_DEC) outs[((size_t)t * 512 + row) * 512 + j] = f2b(hn);
        else if (xl[r] - 1 == t) ctx[row * 1024 + j] = f2b(hn);
    }
}

// ---------------------------------------------------------------------------
// Embedding gather f32 -> bf16 (+ last valid token)
// ---------------------------------------------------------------------------
__global__ void embed_k(const int* __restrict__ x, const int* __restrict__ xlens,
                        const float* __restrict__ emb,
                        u16* __restrict__ embedded, u16* __restrict__ x_last)
{
    int id = blockIdx.x * 256 + threadIdx.x;   // 28*512*128
    if (id >= 28 * 512 * 128) return;
    int e2 = id & 127;
    int tb = id >> 7;
    int b  = tb & 511;
    int t  = tb >> 9;
    int tok = x[b * 28 + t];
    const float* src = emb + (size_t)tok * 256 + e2 * 2;
    u32 v = (u32)f2b(src[0]) | ((u32)f2b(src[1]) << 16);
    *(u32*)(embedded + (size_t)tb * 256 + e2 * 2) = v;
    if (t == xlens[b] - 1)
        *(u32*)(x_last + (size_t)b * 256 + e2 * 2) = v;
}

// ---------------------------------------------------------------------------
// Backward-direction context: single GRU step with h0 = 0.
// ---------------------------------------------------------------------------
__global__ void ctxb_k(const float* __restrict__ gi, const float* __restrict__ bhh,
                       u16* __restrict__ ctx)
{
    int idx = blockIdx.x * 256 + threadIdx.x;
    if (idx >= 512 * 512) return;
    int b = idx >> 9, j = idx & 511;
    int base = b * 1536;
    float r = sigm(gi[base + j] + bhh[j]);
    float z = sigm(gi[base + 512 + j] + bhh[512 + j]);
    float n = tanhf(gi[base + 1024 + j] + r * bhh[1024 + j]);
    ctx[b * 1024 + 512 + j] = f2b((1.f - z) * n);
}

// ---------------------------------------------------------------------------

extern "C" void kernel_launch(void* const* d_in, const int* in_sizes, int n_in,
                              void* d_out, int out_size, void* d_ws, size_t ws_size,
                              hipStream_t stream)
{
    const int*   x      = (const int*)d_in[0];
    const int*   xlens  = (const int*)d_in[1];
    const float* emb    = (const float*)d_in[2];
    const float* Wih_f  = (const float*)d_in[3];
    const float* Whh_f  = (const float*)d_in[4];
    const float* bih_f  = (const float*)d_in[5];
    const float* bhh_f  = (const float*)d_in[6];
    const float* Wih_b  = (const float*)d_in[7];
    const float* bih_b  = (const float*)d_in[9];
    const float* bhh_b  = (const float*)d_in[10];
    const float* fc1_w  = (const float*)d_in[11];
    const float* fc1_b  = (const float*)d_in[12];
    const float* fc2_w  = (const float*)d_in[13];
    const float* fc2_b  = (const float*)d_in[14];
    const float* dWih   = (const float*)d_in[15];
    const float* dWhh   = (const float*)d_in[16];
    const float* dbih   = (const float*)d_in[17];
    const float* dbhh   = (const float*)d_in[18];
    const float* re_w   = (const float*)d_in[19];
    const float* re_b   = (const float*)d_in[20];
    const float* hv_w   = (const float*)d_in[21];
    const float* hv_b   = (const float*)d_in[22];

    float* out        = (float*)d_out;
    float* out_logits = out;                                   // [28,512,32000] f32
    float* out_z      = out + (size_t)28 * 512 * 32000;        // [512,128] f32
    float* out_re     = out_z + 512 * 128;                     // [512,28,256] f32

    // --- ws sub-allocator ---
    char* ws = (char*)d_ws;
    size_t off = 0;
    auto alloc = [&](size_t bytes) -> void* {
        void* p = ws + off; off += (bytes + 255) & ~(size_t)255; return p;
    };
    u16* wWihf = (u16*)alloc(1536 * 256 * 2);
    u16* wWhhf = (u16*)alloc(1536 * 512 * 2);
    u16* wWihb = (u16*)alloc(1536 * 256 * 2);
    u16* wfc1  = (u16*)alloc(128 * 1024 * 2);
    u16* wfc2  = (u16*)alloc(512 * 128 * 2);
    u16* wdWih = (u16*)alloc(1536 * 512 * 2);
    u16* wdWhh = (u16*)alloc(1536 * 512 * 2);
    u16* wre   = (u16*)alloc(256 * 512 * 2);
    u16* whv   = (u16*)alloc((size_t)32000 * 512 * 2);
    u16*   hb0    = (u16*)  alloc(512 * 512 * 2);
    u16*   hb1    = (u16*)  alloc(512 * 512 * 2);
    float* hf0    = (float*)alloc(512 * 512 * 4);
    float* hf1    = (float*)alloc(512 * 512 * 4);
    u16*   ctx    = (u16*)  alloc(512 * 1024 * 2);
    float* gi_bw  = (float*)alloc(512 * 1536 * 4);
    u16*   out_zb = (u16*)  alloc(512 * 128 * 2);
    u16*   gi_dec = (u16*)  alloc(512 * 1536 * 2);
    u16*   outsb  = (u16*)  alloc((size_t)28 * 512 * 512 * 2);

    // --- big transient scratch overlaid into logits region of d_out ---
    char* ds = (char*)d_out;
    size_t doff = 0;
    auto dalloc = [&](size_t bytes) -> void* {
        void* p = ds + doff; doff += (bytes + 255) & ~(size_t)255; return p;
    };
    u16* embedded = (u16*)dalloc((size_t)28 * 512 * 256 * 2);
    u16* x_last   = (u16*)dalloc(512 * 256 * 2);
    u16* gi_f     = (u16*)dalloc((size_t)28 * 512 * 1536 * 2);

    // 0. weight conversion + state init
    auto cvt = [&](const float* s, u16* d, int n) {
        cvt_k<<<(n / 4 + 255) / 256, 256, 0, stream>>>(s, d, n / 4);
    };
    cvt(Wih_f, wWihf, 1536 * 256);
    cvt(Whh_f, wWhhf, 1536 * 512);
    cvt(Wih_b, wWihb, 1536 * 256);
    cvt(fc1_w, wfc1, 128 * 1024);
    cvt(fc2_w, wfc2, 512 * 128);
    cvt(dWih, wdWih, 1536 * 512);
    cvt(dWhh, wdWhh, 1536 * 512);
    cvt(re_w, wre, 256 * 512);
    cvt(hv_w, whv, 32000 * 512);
    hipMemsetAsync(hb0, 0, 512 * 512 * 2, stream);
    hipMemsetAsync(hf0, 0, 512 * 512 * 4, stream);

    // 1. embedding gather
    embed_k<<<7168, 256, 0, stream>>>(x, xlens, emb, embedded, x_last);

    // 2. encoder input gates for all t: gi_f = embedded @ Wih_f^T + bih_f
    gemm_bt<false, false><<<dim3(12, 112), 256, 0, stream>>>(
        embedded, wWihf, bih_f, nullptr, gi_f, 14336, 1536, 256);

    // 3. backward-direction context (off the scan critical path)
    gemm_bt<false, false><<<dim3(12, 4), 256, 0, stream>>>(
        x_last, wWihb, bih_b, gi_bw, nullptr, 512, 1536, 256);
    ctxb_k<<<1024, 256, 0, stream>>>(gi_bw, bhh_b, ctx);

    // 4. forward encoder scan — one fused kernel per step
    {
        u16*   hb[2] = { hb0, hb1 };
        float* hf[2] = { hf0, hf1 };
        for (int t = 0; t < 28; ++t) {
            int s = t & 1, d = s ^ 1;
            scan_step<false><<<256, 256, 0, stream>>>(
                gi_f, wWhhf, bhh_f, hb[s], hf[s], hb[d], hf[d],
                xlens, ctx, nullptr, t);
        }
    }

    // 5. z = context @ fc1_w^T + fc1_b
    gemm_bt<false, false><<<dim3(1, 4), 256, 0, stream>>>(
        ctx, wfc1, fc1_b, out_z, out_zb, 512, 128, 1024);

    // 6. out0 = z @ fc2_w^T + fc2_b  (f32 -> hf0, bf16 -> hb0 = decoder h ping)
    gemm_bt<false, false><<<dim3(4, 4), 256, 0, stream>>>(
        out_zb, wfc2, fc2_b, hf0, hb0, 512, 512, 128);

    // 7. decoder constant input gates: gi_dec = out0 @ dec_Wih^T + dec_bih
    gemm_bt<false, false><<<dim3(12, 4), 256, 0, stream>>>(
        hb0, wdWih, dbih, nullptr, gi_dec, 512, 1536, 512);

    // 8. decoder scan — one fused kernel per step
    {
        u16*   hb[2] = { hb0, hb1 };
        float* hf[2] = { hf0, hf1 };
        for (int t = 0; t < 28; ++t) {
            int s = t & 1, d = s ^ 1;
            scan_step<true><<<256, 256, 0, stream>>>(
                gi_dec, wdWhh, dbhh, hb[s], hf[s], hb[d], hf[d],
                nullptr, nullptr, outsb, t);
        }
    }

    // 9. re_emb = leakyrelu(outs @ re_w^T + re_b), [T,B]->[B,T]
    gemm_bt<true, true><<<dim3(2, 112), 256, 0, stream>>>(
        outsb, wre, re_b, out_re, nullptr, 14336, 256, 512);

    // 10. logits = outs @ hv_w^T + hv_b  (overwrites d_out scratch)
    gemm_bt<false, false><<<dim3(250, 112), 256, 0, stream>>>(
        outsb, whv, hv_b, out_logits, nullptr, 14336, 32000, 512);
}

// Round 5
// 1353.458 us; speedup vs baseline: 3.2122x; 1.0941x over previous
//
#include <hip/hip_runtime.h>

typedef unsigned short u16;
typedef unsigned int u32;
typedef __attribute__((ext_vector_type(8))) short bf16x8;
typedef __attribute__((ext_vector_type(4))) float f32x4;

#define GLOBAL_AS __attribute__((address_space(1)))
#define LDS_AS __attribute__((address_space(3)))

__device__ __forceinline__ float b2f(u16 u) {
    union { float f; u32 i; } v; v.i = ((u32)u) << 16; return v.f;
}
__device__ __forceinline__ u16 f2b(float f) {
    union { float f; u32 i; } v; v.f = f;
    u32 i = v.i;
    u32 r = (i + 0x7FFFu + ((i >> 16) & 1u)) >> 16;
    return (u16)r;
}
__device__ __forceinline__ float sigm(float x) { return 1.f / (1.f + expf(-x)); }

// ---------------------------------------------------------------------------
// f32 -> bf16 converter (n multiple of 4)
// ---------------------------------------------------------------------------
__global__ void cvt_k(const float* __restrict__ src, u16* __restrict__ dst, int n4)
{
    int id = blockIdx.x * 256 + threadIdx.x;
    if (id >= n4) return;
    float4 v = ((const float4*)src)[id];
    u32 w0 = (u32)f2b(v.x) | ((u32)f2b(v.y) << 16);
    u32 w1 = (u32)f2b(v.z) | ((u32)f2b(v.w) << 16);
    ((u32*)dst)[id * 2]     = w0;
    ((u32*)dst)[id * 2 + 1] = w1;
}

// ---------------------------------------------------------------------------
// Generic GEMM: C[M,N] = A[M,K] @ W[N,K]^T + bias[N]   (m97-pattern, verified)
// ---------------------------------------------------------------------------
template<bool LEAKY, bool REMAP>
__global__ __launch_bounds__(256)
void gemm_bt(const u16* __restrict__ A, const u16* __restrict__ W,
             const float* __restrict__ bias,
             float* __restrict__ Cf, u16* __restrict__ Cb,
             int M, int N, int K)
{
    __shared__ __align__(16) u16 lA[128 * 64];
    __shared__ __align__(16) u16 lB[128 * 64];

    const int tid  = threadIdx.x;
    const int lane = tid & 63;
    const int w    = tid >> 6;
    const int wr   = w >> 1;
    const int wc   = w & 1;
    const int m0   = blockIdx.y * 128;
    const int n0   = blockIdx.x * 128;

    const int lrow = lane & 15;
    const int kgrp = lane >> 4;

    f32x4 acc[4][4] = {};

    for (int k0 = 0; k0 < K; k0 += 64) {
        #pragma unroll
        for (int s = 0; s < 4; ++s) {
            int seg = w * 4 + s;
            int g   = seg * 64 + lane;
            int row = g >> 3;
            int kk  = (g & 7) * 8;
            const u16* gA = A + (size_t)(m0 + row) * K + k0 + kk;
            const u16* gB = W + (size_t)(n0 + row) * K + k0 + kk;
            __builtin_amdgcn_global_load_lds((GLOBAL_AS const void*)gA,
                                             (LDS_AS void*)(&lA[seg * 512]), 16, 0, 0);
            __builtin_amdgcn_global_load_lds((GLOBAL_AS const void*)gB,
                                             (LDS_AS void*)(&lB[seg * 512]), 16, 0, 0);
        }
        __syncthreads();
        #pragma unroll
        for (int kk = 0; kk < 64; kk += 32) {
            bf16x8 af[4], bfr[4];
            #pragma unroll
            for (int i = 0; i < 4; ++i) {
                int ar = wr * 64 + i * 16 + lrow;
                af[i]  = *(const bf16x8*)&lA[ar * 64 + kk + kgrp * 8];
                int br = wc * 64 + i * 16 + lrow;
                bfr[i] = *(const bf16x8*)&lB[br * 64 + kk + kgrp * 8];
            }
            #pragma unroll
            for (int mi = 0; mi < 4; ++mi)
                #pragma unroll
                for (int ni = 0; ni < 4; ++ni)
                    acc[mi][ni] = __builtin_amdgcn_mfma_f32_16x16x32_bf16(
                        af[mi], bfr[ni], acc[mi][ni], 0, 0, 0);
        }
        __syncthreads();
    }

    #pragma unroll
    for (int mi = 0; mi < 4; ++mi) {
        #pragma unroll
        for (int ni = 0; ni < 4; ++ni) {
            int gcol = n0 + wc * 64 + ni * 16 + lrow;
            float bv = bias ? bias[gcol] : 0.f;
            #pragma unroll
            for (int r = 0; r < 4; ++r) {
                int grow = m0 + wr * 64 + mi * 16 + kgrp * 4 + r;
                float v = acc[mi][ni][r] + bv;
                if (LEAKY) v = (v >= 0.f) ? v : 0.02f * v;
                size_t oidx;
                if (REMAP) {
                    int bb = grow & 511, tt = grow >> 9;
                    oidx = ((size_t)bb * 28 + tt) * (size_t)N + gcol;
                } else {
                    oidx = (size_t)grow * (size_t)N + gcol;
                }
                if (Cf) Cf[oidx] = v;
                if (Cb) Cb[oidx] = f2b(v);
            }
        }
    }
}

// ---------------------------------------------------------------------------
// Pipelined 256x256 GEMM for the logits: C[M,N] = A[M,K=512] @ W[N,512]^T + bias
// 512 threads (8 waves 2Mx4N), BK=32 (16 K-tiles), triple-buffered LDS (96 KB),
// counted vmcnt(4) gate + ONE raw s_barrier per K-tile, swizzled ds_read_b128,
// setprio around MFMA cluster. XCD-chunked block swizzle (grid 7000 = 8*875).
// ---------------------------------------------------------------------------
__global__ __launch_bounds__(512)
void gemm_logits(const u16* __restrict__ A, const u16* __restrict__ W,
                 const float* __restrict__ bias, float* __restrict__ C,
                 int M, int N)
{
    constexpr int K = 512;
    __shared__ __align__(16) u16 lds[3 * 2 * 8192];   // 3 bufs x (A 16KB + B 16KB)

    const int tid  = threadIdx.x;
    const int lane = tid & 63;
    const int w    = tid >> 6;          // 0..7
    const int wr   = w >> 2;            // 0..1  (M half: 128 rows)
    const int wc   = w & 3;             // 0..3  (N quarter: 64 cols)
    const int l15  = lane & 15;
    const int kg   = lane >> 4;         // 0..3

    // XCD-chunked swizzle (bijective: 7000 % 8 == 0)
    int id = blockIdx.x;
    int sw = (id & 7) * (7000 / 8) + (id >> 3);
    const int by = sw / 125;            // M tile 0..55
    const int bx = sw % 125;            // N tile 0..124
    const int m0 = by * 256;
    const int n0 = bx * 256;

    // stage one K-tile (A 16KB + B 16KB) into buffer buf: 4 loads/thread
    auto stage = [&](int kt, int buf) {
        #pragma unroll
        for (int ld = 0; ld < 2; ++ld) {
            int g   = ld * 512 + tid;       // chunk id 0..1023
            int row = g >> 2;               // 0..255
            int cp  = g & 3;                // 16B chunk within 64B row
            int scp = cp ^ ((row >> 1) & 3);
            const u16* sA = A + (size_t)(m0 + row) * K + kt * 32 + scp * 8;
            const u16* sB = W + (size_t)(n0 + row) * K + kt * 32 + scp * 8;
            u32 dst = (u32)buf * 32768u + (u32)(ld * 512 + w * 64) * 16u;
            __builtin_amdgcn_global_load_lds((GLOBAL_AS const void*)sA,
                (LDS_AS void*)((char*)lds + dst), 16, 0, 0);
            __builtin_amdgcn_global_load_lds((GLOBAL_AS const void*)sB,
                (LDS_AS void*)((char*)lds + dst + 16384u), 16, 0, 0);
        }
    };

    f32x4 acc[8][4] = {};

    // compute one K-tile from buffer buf: 12 ds_read_b128 + 32 MFMA
    auto compute = [&](int buf) {
        const char* base = (const char*)lds + buf * 32768;
        bf16x8 a[8], b[4];
        #pragma unroll
        for (int mi = 0; mi < 8; ++mi) {
            int r = wr * 128 + mi * 16 + l15;
            a[mi] = *(const bf16x8*)(base + r * 64 + ((kg ^ ((r >> 1) & 3)) << 4));
        }
        #pragma unroll
        for (int ni = 0; ni < 4; ++ni) {
            int r = wc * 64 + ni * 16 + l15;
            b[ni] = *(const bf16x8*)(base + 16384 + r * 64 + ((kg ^ ((r >> 1) & 3)) << 4));
        }
        __builtin_amdgcn_s_setprio(1);
        #pragma unroll
        for (int mi = 0; mi < 8; ++mi)
            #pragma unroll
            for (int ni = 0; ni < 4; ++ni)
                acc[mi][ni] = __builtin_amdgcn_mfma_f32_16x16x32_bf16(
                    a[mi], b[ni], acc[mi][ni], 0, 0, 0);
        __builtin_amdgcn_s_setprio(0);
    };

    // prologue: tiles 0 and 1 in flight (8 loads/thread)
    stage(0, 0);
    stage(1, 1);

    int b0 = 0, b1 = 1, b2 = 2;
    #pragma unroll 1
    for (int kt = 0; kt < 14; ++kt) {
        asm volatile("s_waitcnt vmcnt(4)" ::: "memory");   // tile kt fully in LDS
        __builtin_amdgcn_sched_barrier(0);
        __builtin_amdgcn_s_barrier();                      // all waves: kt ready, b2 free
        asm volatile("" ::: "memory");
        __builtin_amdgcn_sched_barrier(0);
        stage(kt + 2, b2);
        compute(b0);
        int t = b0; b0 = b1; b1 = b2; b2 = t;
    }
    // kt = 14 (no more staging; stage(15) = newest 4 outstanding)
    asm volatile("s_waitcnt vmcnt(4)" ::: "memory");
    __builtin_amdgcn_sched_barrier(0);
    __builtin_amdgcn_s_barrier();
    asm volatile("" ::: "memory");
    __builtin_amdgcn_sched_barrier(0);
    compute(b0);
    { int t = b0; b0 = b1; b1 = b2; b2 = t; }
    // kt = 15
    asm volatile("s_waitcnt vmcnt(0)" ::: "memory");
    __builtin_amdgcn_sched_barrier(0);
    __builtin_amdgcn_s_barrier();
    asm volatile("" ::: "memory");
    __builtin_amdgcn_sched_barrier(0);
    compute(b0);

    // epilogue: C = acc + bias (f32)
    #pragma unroll
    for (int ni = 0; ni < 4; ++ni) {
        int gcol = n0 + wc * 64 + ni * 16 + l15;
        float bv = bias[gcol];
        #pragma unroll
        for (int mi = 0; mi < 8; ++mi) {
            #pragma unroll
            for (int r = 0; r < 4; ++r) {
                int grow = m0 + wr * 128 + mi * 16 + kg * 4 + r;
                C[(size_t)grow * (size_t)N + gcol] = acc[mi][ni][r] + bv;
            }
        }
    }
}

// ---------------------------------------------------------------------------
// Fused GRU scan step — ONE kernel per time step (kernel boundary = sync).
// ---------------------------------------------------------------------------
template<bool IS_DEC>
__global__ __launch_bounds__(256)
void scan_step(const u16* __restrict__ gi,      // enc: [28][512][1536]; dec: [512][1536]
               const u16* __restrict__ Whh,     // [1536][512] bf16
               const float* __restrict__ bhh,   // [1536] f32
               const u16* __restrict__ hprev_b, // [512][512] bf16
               const float* __restrict__ hprev_f,// [512][512] f32
               u16* __restrict__ hnext_b,
               float* __restrict__ hnext_f,
               const int* __restrict__ xlens,   // enc only
               u16* __restrict__ ctx,           // enc: [512][1024] (first half)
               u16* __restrict__ outs,          // dec: [28][512][512] bf16
               int t)
{
    __shared__ __align__(16) u16 lB[96 * 512];   // 96 KB
    __shared__ __align__(16) u16 lA[32 * 512];   // 32 KB

    const int tid  = threadIdx.x;
    const int lane = tid & 63;
    const int w    = tid >> 6;
    const int rh   = w >> 1;
    const int jh   = w & 1;
    const int bc   = blockIdx.x >> 4;
    const int jc   = blockIdx.x & 15;

    const int l15 = lane & 15;
    const int kg  = lane >> 4;

    #pragma unroll
    for (int s = 0; s < 24; ++s) {
        int g    = s * 256 + tid;
        int rr   = g >> 6;
        int cp   = g & 63;
        int gate = rr >> 5;
        int c    = rr & 31;
        int whrow = gate * 512 + jc * 32 + c;
        const u16* src = Whh + (size_t)whrow * 512 + (size_t)((cp ^ (rr & 7)) * 8);
        __builtin_amdgcn_global_load_lds((GLOBAL_AS const void*)src,
            (LDS_AS void*)((char*)lB + (s * 256 + w * 64) * 16), 16, 0, 0);
    }
    #pragma unroll
    for (int s = 0; s < 8; ++s) {
        int g   = s * 256 + tid;
        int row = g >> 6;
        int cp  = g & 63;
        const u16* src = hprev_b + (size_t)(bc * 32 + row) * 512
                                 + (size_t)((cp ^ (row & 7)) * 8);
        __builtin_amdgcn_global_load_lds((GLOBAL_AS const void*)src,
            (LDS_AS void*)((char*)lA + (s * 256 + w * 64) * 16), 16, 0, 0);
    }

    const int jloc = jh * 16 + l15;
    const int j    = jc * 32 + jloc;
    const int rowb = bc * 32 + rh * 16 + kg * 4;
    const float bhr = bhh[j], bhz = bhh[512 + j], bhn = bhh[1024 + j];

    const u16* gi_t = IS_DEC ? gi : gi + (size_t)t * 512 * 1536;
    float gir[4], giz[4], gin[4], hold[4];
    int   xl[4];
    #pragma unroll
    for (int r = 0; r < 4; ++r) {
        int row = rowb + r;
        gir[r]  = b2f(gi_t[row * 1536 + j]);
        giz[r]  = b2f(gi_t[row * 1536 + 512 + j]);
        gin[r]  = b2f(gi_t[row * 1536 + 1024 + j]);
        hold[r] = hprev_f[row * 512 + j];
        if (!IS_DEC) xl[r] = xlens[row];
    }
    __syncthreads();

    f32x4 acc[3] = {};
    const int arow = rh * 16 + l15;
    #pragma unroll 4
    for (int kc = 0; kc < 16; ++kc) {
        int k2 = kc * 64 + kg * 16;
        bf16x8 a = *(const bf16x8*)((const char*)lA + arow * 1024
                                    + (k2 ^ ((arow & 7) << 4)));
        #pragma unroll
        for (int g3 = 0; g3 < 3; ++g3) {
            int rr = g3 * 32 + jloc;
            bf16x8 b = *(const bf16x8*)((const char*)lB + rr * 1024
                                        + (k2 ^ ((rr & 7) << 4)));
            acc[g3] = __builtin_amdgcn_mfma_f32_16x16x32_bf16(a, b, acc[g3], 0, 0, 0);
        }
    }

    #pragma unroll
    for (int r = 0; r < 4; ++r) {
        int row = rowb + r;
        float rg = sigm(gir[r] + acc[0][r] + bhr);
        float zg = sigm(giz[r] + acc[1][r] + bhz);
        float ng = tanhf(gin[r] + rg * (acc[2][r] + bhn));
        float hn = (1.f - zg) * ng + zg * hold[r];
        hnext_f[row * 512 + j] = hn;
        hnext_b[row * 512 + j] = f2b(hn);
        if (IS_DEC) outs[((size_t)t * 512 + row) * 512 + j] = f2b(hn);
        else if (xl[r] - 1 == t) ctx[row * 1024 + j] = f2b(hn);
    }
}

// ---------------------------------------------------------------------------
// Embedding gather f32 -> bf16 (+ last valid token)
// ---------------------------------------------------------------------------
__global__ void embed_k(const int* __restrict__ x, const int* __restrict__ xlens,
                        const float* __restrict__ emb,
                        u16* __restrict__ embedded, u16* __restrict__ x_last)
{
    int id = blockIdx.x * 256 + threadIdx.x;   // 28*512*128
    if (id >= 28 * 512 * 128) return;
    int e2 = id & 127;
    int tb = id >> 7;
    int b  = tb & 511;
    int t  = tb >> 9;
    int tok = x[b * 28 + t];
    const float* src = emb + (size_t)tok * 256 + e2 * 2;
    u32 v = (u32)f2b(src[0]) | ((u32)f2b(src[1]) << 16);
    *(u32*)(embedded + (size_t)tb * 256 + e2 * 2) = v;
    if (t == xlens[b] - 1)
        *(u32*)(x_last + (size_t)b * 256 + e2 * 2) = v;
}

// ---------------------------------------------------------------------------
// Backward-direction context: single GRU step with h0 = 0.
// ---------------------------------------------------------------------------
__global__ void ctxb_k(const float* __restrict__ gi, const float* __restrict__ bhh,
                       u16* __restrict__ ctx)
{
    int idx = blockIdx.x * 256 + threadIdx.x;
    if (idx >= 512 * 512) return;
    int b = idx >> 9, j = idx & 511;
    int base = b * 1536;
    float r = sigm(gi[base + j] + bhh[j]);
    float z = sigm(gi[base + 512 + j] + bhh[512 + j]);
    float n = tanhf(gi[base + 1024 + j] + r * bhh[1024 + j]);
    ctx[b * 1024 + 512 + j] = f2b((1.f - z) * n);
}

// ---------------------------------------------------------------------------

extern "C" void kernel_launch(void* const* d_in, const int* in_sizes, int n_in,
                              void* d_out, int out_size, void* d_ws, size_t ws_size,
                              hipStream_t stream)
{
    const int*   x      = (const int*)d_in[0];
    const int*   xlens  = (const int*)d_in[1];
    const float* emb    = (const float*)d_in[2];
    const float* Wih_f  = (const float*)d_in[3];
    const float* Whh_f  = (const float*)d_in[4];
    const float* bih_f  = (const float*)d_in[5];
    const float* bhh_f  = (const float*)d_in[6];
    const float* Wih_b  = (const float*)d_in[7];
    const float* bih_b  = (const float*)d_in[9];
    const float* bhh_b  = (const float*)d_in[10];
    const float* fc1_w  = (const float*)d_in[11];
    const float* fc1_b  = (const float*)d_in[12];
    const float* fc2_w  = (const float*)d_in[13];
    const float* fc2_b  = (const float*)d_in[14];
    const float* dWih   = (const float*)d_in[15];
    const float* dWhh   = (const float*)d_in[16];
    const float* dbih   = (const float*)d_in[17];
    const float* dbhh   = (const float*)d_in[18];
    const float* re_w   = (const float*)d_in[19];
    const float* re_b   = (const float*)d_in[20];
    const float* hv_w   = (const float*)d_in[21];
    const float* hv_b   = (const float*)d_in[22];

    float* out        = (float*)d_out;
    float* out_logits = out;                                   // [28,512,32000] f32
    float* out_z      = out + (size_t)28 * 512 * 32000;        // [512,128] f32
    float* out_re     = out_z + 512 * 128;                     // [512,28,256] f32

    // --- ws sub-allocator ---
    char* ws = (char*)d_ws;
    size_t off = 0;
    auto alloc = [&](size_t bytes) -> void* {
        void* p = ws + off; off += (bytes + 255) & ~(size_t)255; return p;
    };
    u16* wWihf = (u16*)alloc(1536 * 256 * 2);
    u16* wWhhf = (u16*)alloc(1536 * 512 * 2);
    u16* wWihb = (u16*)alloc(1536 * 256 * 2);
    u16* wfc1  = (u16*)alloc(128 * 1024 * 2);
    u16* wfc2  = (u16*)alloc(512 * 128 * 2);
    u16* wdWih = (u16*)alloc(1536 * 512 * 2);
    u16* wdWhh = (u16*)alloc(1536 * 512 * 2);
    u16* wre   = (u16*)alloc(256 * 512 * 2);
    u16* whv   = (u16*)alloc((size_t)32000 * 512 * 2);
    u16*   hb0    = (u16*)  alloc(512 * 512 * 2);
    u16*   hb1    = (u16*)  alloc(512 * 512 * 2);
    float* hf0    = (float*)alloc(512 * 512 * 4);
    float* hf1    = (float*)alloc(512 * 512 * 4);
    u16*   ctx    = (u16*)  alloc(512 * 1024 * 2);
    float* gi_bw  = (float*)alloc(512 * 1536 * 4);
    u16*   out_zb = (u16*)  alloc(512 * 128 * 2);
    u16*   gi_dec = (u16*)  alloc(512 * 1536 * 2);
    u16*   outsb  = (u16*)  alloc((size_t)28 * 512 * 512 * 2);

    // --- big transient scratch overlaid into logits region of d_out ---
    char* ds = (char*)d_out;
    size_t doff = 0;
    auto dalloc = [&](size_t bytes) -> void* {
        void* p = ds + doff; doff += (bytes + 255) & ~(size_t)255; return p;
    };
    u16* embedded = (u16*)dalloc((size_t)28 * 512 * 256 * 2);
    u16* x_last   = (u16*)dalloc(512 * 256 * 2);
    u16* gi_f     = (u16*)dalloc((size_t)28 * 512 * 1536 * 2);

    // 0. weight conversion + state init
    auto cvt = [&](const float* s, u16* d, int n) {
        cvt_k<<<(n / 4 + 255) / 256, 256, 0, stream>>>(s, d, n / 4);
    };
    cvt(Wih_f, wWihf, 1536 * 256);
    cvt(Whh_f, wWhhf, 1536 * 512);
    cvt(Wih_b, wWihb, 1536 * 256);
    cvt(fc1_w, wfc1, 128 * 1024);
    cvt(fc2_w, wfc2, 512 * 128);
    cvt(dWih, wdWih, 1536 * 512);
    cvt(dWhh, wdWhh, 1536 * 512);
    cvt(re_w, wre, 256 * 512);
    cvt(hv_w, whv, 32000 * 512);
    hipMemsetAsync(hb0, 0, 512 * 512 * 2, stream);
    hipMemsetAsync(hf0, 0, 512 * 512 * 4, stream);

    // 1. embedding gather
    embed_k<<<7168, 256, 0, stream>>>(x, xlens, emb, embedded, x_last);

    // 2. encoder input gates for all t: gi_f = embedded @ Wih_f^T + bih_f
    gemm_bt<false, false><<<dim3(12, 112), 256, 0, stream>>>(
        embedded, wWihf, bih_f, nullptr, gi_f, 14336, 1536, 256);

    // 3. backward-direction context (off the scan critical path)
    gemm_bt<false, false><<<dim3(12, 4), 256, 0, stream>>>(
        x_last, wWihb, bih_b, gi_bw, nullptr, 512, 1536, 256);
    ctxb_k<<<1024, 256, 0, stream>>>(gi_bw, bhh_b, ctx);

    // 4. forward encoder scan — one fused kernel per step
    {
        u16*   hb[2] = { hb0, hb1 };
        float* hf[2] = { hf0, hf1 };
        for (int t = 0; t < 28; ++t) {
            int s = t & 1, d = s ^ 1;
            scan_step<false><<<256, 256, 0, stream>>>(
                gi_f, wWhhf, bhh_f, hb[s], hf[s], hb[d], hf[d],
                xlens, ctx, nullptr, t);
        }
    }

    // 5. z = context @ fc1_w^T + fc1_b
    gemm_bt<false, false><<<dim3(1, 4), 256, 0, stream>>>(
        ctx, wfc1, fc1_b, out_z, out_zb, 512, 128, 1024);

    // 6. out0 = z @ fc2_w^T + fc2_b  (f32 -> hf0, bf16 -> hb0 = decoder h ping)
    gemm_bt<false, false><<<dim3(4, 4), 256, 0, stream>>>(
        out_zb, wfc2, fc2_b, hf0, hb0, 512, 512, 128);

    // 7. decoder constant input gates: gi_dec = out0 @ dec_Wih^T + dec_bih
    gemm_bt<false, false><<<dim3(12, 4), 256, 0, stream>>>(
        hb0, wdWih, dbih, nullptr, gi_dec, 512, 1536, 512);

    // 8. decoder scan — one fused kernel per step
    {
        u16*   hb[2] = { hb0, hb1 };
        float* hf[2] = { hf0, hf1 };
        for (int t = 0; t < 28; ++t) {
            int s = t & 1, d = s ^ 1;
            scan_step<true><<<256, 256, 0, stream>>>(
                gi_dec, wdWhh, dbhh, hb[s], hf[s], hb[d], hf[d],
                nullptr, nullptr, outsb, t);
        }
    }

    // 9. re_emb = leakyrelu(outs @ re_w^T + re_b), [T,B]->[B,T]
    gemm_bt<true, true><<<dim3(2, 112), 256, 0, stream>>>(
        outsb, wre, re_b, out_re, nullptr, 14336, 256, 512);

    // 10. logits = outs @ hv_w^T + hv_b  (pipelined 256² kernel; overwrites scratch)
    gemm_logits<<<7000, 512, 0, stream>>>(
        outsb, whv, hv_b, out_logits, 14336, 32000);
}